// Round 14
// baseline (140.328 us; speedup 1.0000x reference)
//
#include <hip/hip_runtime.h>

#define LN_EPS 1e-5f
#define DD 128
#define TWO_D 256
#define HH 64
#define PPB 512   // pairs per block in fallback k_pairs

typedef unsigned int uint;
typedef unsigned short ushort;
typedef unsigned long long ull;
typedef __attribute__((ext_vector_type(8))) short short8v;   // 8 bf16 (4 VGPRs)
typedef __attribute__((ext_vector_type(4))) float f32x4;     // MFMA accumulator

__device__ __forceinline__ ushort f2bf(float f) {
    uint u = __float_as_uint(f);
    u += 0x7FFFu + ((u >> 16) & 1u);  // round-to-nearest-even
    return (ushort)(u >> 16);
}
__device__ __forceinline__ float bf2f(ushort h) {
    return __uint_as_float(((uint)h) << 16);
}
__device__ __forceinline__ int clampi(int v, int lo, int hi) {
    return v < lo ? lo : (v > hi ? hi : v);
}
// Gather the 8 LSBs of the 8 bytes in (a,b); byte pos k' -> bit (7-k') of result
__device__ __forceinline__ uint lsb8(uint a, uint b) {
    uint nx = (((a & 0x01010101u) * 0x08040201u) >> 24) & 0xFu;
    uint ny = (((b & 0x01010101u) * 0x08040201u) >> 24) & 0xFu;
    return (nx << 4) | ny;
}
// Hardware XCD id (0..7) — wave-uniform SGPR read [measured: learn_hip m09]
__device__ __forceinline__ uint get_xcc() {
    uint x;
    asm volatile("s_getreg_b32 %0, hwreg(HW_REG_XCC_ID)" : "=s"(x));
    return x & 7u;
}

// ---------------- fused proj (unchanged): block 0 = prep; 128 rows/block MFMA;
// 64B int8 rows, h-permuted (byte k holds h=(k&3)*16+(k>>2)); bytes 0..31 are 7-bit,
// LSBs carry payload S_q8 | Q_q8<<8 | bf16(scale)<<16.
// GB floats: [0..63] G, [64..127] B1c, [128..191] Gp, [192..255] Bp, [256..319] Wp
__global__ __launch_bounds__(256) void k_fused(
    const float* __restrict__ node_feat, int n_nodes, int nbN,
    const float* __restrict__ edge_feat, int n_edges,
    const float* __restrict__ gamma, const float* __restrict__ beta,
    const float* __restrict__ W1, const float* __restrict__ b1,
    const float* __restrict__ W2,
    signed char* __restrict__ node_pt, signed char* __restrict__ edge_pt,
    float* __restrict__ GB) {
    int bid = blockIdx.x;
    int tid = threadIdx.x;

    if (bid == 0) {
        if (tid < 128) {
            int h = tid & 63;
            bool isB = tid >= 64;
            float acc = isB ? b1[h] : 0.f;
            const float* coef = isB ? beta : gamma;
#pragma unroll 8
            for (int d = 0; d < TWO_D; ++d)
                acc = fmaf(coef[d], W1[d * HH + h], acc);
            GB[tid] = acc;
        }
        __syncthreads();
        if (tid < 64) {
            int h = ((tid & 3) * 16) + (tid >> 2);   // byte pos tid holds h
            GB[128 + tid] = GB[h];
            GB[192 + tid] = GB[64 + h];
            GB[256 + tid] = W2[h];
        }
        return;
    }

    const float* feat;
    int nrows, gofs, rbase0;
    signed char* pt;
    if (bid <= nbN) {
        feat = node_feat; nrows = n_nodes; gofs = 128;
        rbase0 = (bid - 1) * 128; pt = node_pt;
    } else {
        feat = edge_feat; nrows = n_edges; gofs = 0;
        rbase0 = (bid - 1 - nbN) * 128; pt = edge_pt;
    }

    __shared__ __align__(16) char lds[49664];
    uint* sqLDS = (uint*)(lds + 49152);

    {
        int l = tid & 63;
        int w = tid >> 6;
#pragma unroll
        for (int ci = 0; ci < 4; ++ci) {
            int combo = ci * 4 + w;
            int ks = combo & 3;
            int ht = combo >> 2;
            int kbase = gofs + ks * 32 + (l >> 4) * 8;
            int h = ht * 16 + (l & 15);
            short8v v;
#pragma unroll
            for (int j = 0; j < 8; ++j)
                v[j] = (short)f2bf(gamma[kbase + j] * W1[(size_t)(kbase + j) * HH + h]);
            *(short8v*)(lds + 32768 + combo * 1024 + l * 16) = v;
        }
    }

    {
        float4 tmp[16];
#pragma unroll
        for (int u = 0; u < 16; ++u) {
            int F4 = u * 256 + tid;
            int r = F4 >> 5;
            int rg = rbase0 + r;
            rg = rg < nrows ? rg : (nrows - 1);
            int c4 = (F4 & 31) * 4;
            tmp[u] = *(const float4*)&feat[(size_t)rg * DD + c4];
        }
#pragma unroll
        for (int u = 0; u < 16; ++u) {
            int F4 = u * 256 + tid;
            int r = F4 >> 5;
            int c4 = (F4 & 31) * 4;
            uint2 wv;
            wv.x = (uint)f2bf(tmp[u].x) | ((uint)f2bf(tmp[u].y) << 16);
            wv.y = (uint)f2bf(tmp[u].z) | ((uint)f2bf(tmp[u].w) << 16);
            int byte = (r * 256 + c4 * 2) ^ ((r & 7) << 4);
            *(uint2*)(lds + byte) = wv;
        }
    }

    __syncthreads();

    int w = tid >> 6;
    int lane = tid & 63;
    f32x4 acc[2][4];
#pragma unroll
    for (int i = 0; i < 2; ++i)
#pragma unroll
        for (int j = 0; j < 4; ++j) acc[i][j] = (f32x4){0.f, 0.f, 0.f, 0.f};

    int arow_lo = lane & 15;
    int akofs = (lane >> 4) * 8;
#pragma unroll
    for (int ks = 0; ks < 4; ++ks) {
        int kk = ks * 32 + akofs;
        int rr0 = (2 * w) * 16 + arow_lo;
        int rr1 = rr0 + 16;
        short8v a0 = *(const short8v*)(lds + ((rr0 * 256 + kk * 2) ^ ((rr0 & 7) << 4)));
        short8v a1 = *(const short8v*)(lds + ((rr1 * 256 + kk * 2) ^ ((rr1 & 7) << 4)));
#pragma unroll
        for (int ht = 0; ht < 4; ++ht) {
            short8v b = *(const short8v*)(lds + 32768 + (ht * 4 + ks) * 1024 + lane * 16);
            acc[0][ht] = __builtin_amdgcn_mfma_f32_16x16x32_bf16(a0, b, acc[0][ht], 0, 0, 0);
            acc[1][ht] = __builtin_amdgcn_mfma_f32_16x16x32_bf16(a1, b, acc[1][ht], 0, 0, 0);
        }
    }

    {
        int row = tid >> 1, half = tid & 1;
        float s = 0.f, q = 0.f;
#pragma unroll
        for (int i = 0; i < 8; ++i) {
            int byte = (row * 256 + half * 128 + i * 16) ^ ((row & 7) << 4);
            short8v v = *(const short8v*)(lds + byte);
#pragma unroll
            for (int j = 0; j < 8; ++j) {
                float x = bf2f((ushort)v[j]);
                s += x;
                q = fmaf(x, x, q);
            }
        }
        s += __shfl_xor(s, 1);
        q += __shfl_xor(q, 1);
        if (half == 0) {
            int sq = clampi(__float2int_rn(2.0f * s), -127, 127);
            int qq = clampi(__float2int_rn((q - 128.0f) * (1.0f / 0.75f)), -127, 127);
            sqLDS[row] = ((uint)sq & 0xFFu) | (((uint)qq & 0xFFu) << 8);
        }
    }

    __syncthreads();

    {
        int colh = lane & 15;
        int rquad = lane >> 4;
#pragma unroll
        for (int rt = 0; rt < 2; ++rt)
#pragma unroll
            for (int reg = 0; reg < 4; ++reg) {
                float m = fmaxf(fmaxf(fabsf(acc[rt][0][reg]), fabsf(acc[rt][1][reg])),
                                fmaxf(fabsf(acc[rt][2][reg]), fabsf(acc[rt][3][reg])));
                m = fmaxf(m, __shfl_xor(m, 1));
                m = fmaxf(m, __shfl_xor(m, 2));
                m = fmaxf(m, __shfl_xor(m, 4));
                m = fmaxf(m, __shfl_xor(m, 8));
                m = fmaxf(m, 1e-20f);
                float inv = 127.0f / m;
                int rl = (2 * w + rt) * 16 + rquad * 4 + reg;
                uint P = sqLDS[rl] | ((uint)f2bf(m * (1.0f / 127.0f)) << 16);
                uint pk = 0;
#pragma unroll
                for (int ht = 0; ht < 4; ++ht) {
                    uint byte;
                    if (colh < 8) {
                        int kpos = colh * 4 + ht;
                        uint V = (P >> (8 * (kpos >> 3))) & 0xFFu;
                        uint bit = (V >> (7 - (kpos & 7))) & 1u;
                        int q7 = clampi(__float2int_rn(acc[rt][ht][reg] * inv * 0.5f), -63, 63);
                        byte = (((uint)q7 << 1) | bit) & 0xFFu;
                    } else {
                        byte = (uint)__float2int_rn(acc[rt][ht][reg] * inv) & 0xFFu;
                    }
                    pk |= byte << (8 * ht);
                }
                if (rbase0 + rl < nrows)
                    *(uint*)&pt[(size_t)(rbase0 + rl) * 64 + colh * 4] = pk;
            }
    }
}

// ---------------- binning pass 1: wave-aggregated histogram (ballot+popcount,
// 8 LDS atomics per wave-iter instead of 64 per-lane)
__global__ __launch_bounds__(256) void k_hist(const int* __restrict__ node_idx, int E,
                                              int chunk, float scale,
                                              uint* __restrict__ hist) {
    __shared__ uint lc[8];
    int tid = threadIdx.x;
    int lane = tid & 63;
    if (tid < 8) lc[tid] = 0;
    __syncthreads();
    int s = blockIdx.x * chunk;
    int e = s + chunk < E ? s + chunk : E;
    for (int p = s + tid; p < s + ((chunk + 255) & ~255); p += 256) {
        int b = -1;
        if (p < e) {
            int ni = __builtin_nontemporal_load(&node_idx[p]);
            b = (int)((float)ni * scale);
            b = b < 7 ? b : 7;
        }
#pragma unroll
        for (int bb = 0; bb < 8; ++bb) {
            ull m = __ballot(b == bb);
            if (lane == 0 && m) atomicAdd(&lc[bb], (uint)__popcll(m));
        }
    }
    __syncthreads();
    if (tid < 8) hist[blockIdx.x * 8 + tid] = lc[tid];
}

// ---------------- binning pass 2: prefix-scan 256x8 (one block); also zeroes qtail
__global__ __launch_bounds__(256) void k_scan(const uint* __restrict__ hist,
                                              uint* __restrict__ offs,
                                              uint* __restrict__ bstart,
                                              uint* __restrict__ qtail) {
    __shared__ uint sc[256][8];
    __shared__ uint bs_l[9];
    int t = threadIdx.x;
    uint orig[8];
#pragma unroll
    for (int b = 0; b < 8; ++b) {
        orig[b] = hist[t * 8 + b];
        sc[t][b] = orig[b];
    }
    __syncthreads();
    for (int d = 1; d < 256; d <<= 1) {
        uint v[8];
        bool has = t >= d;
        if (has) {
#pragma unroll
            for (int b = 0; b < 8; ++b) v[b] = sc[t - d][b];
        }
        __syncthreads();
        if (has) {
#pragma unroll
            for (int b = 0; b < 8; ++b) sc[t][b] += v[b];
        }
        __syncthreads();
    }
    if (t == 0) {
        uint bs = 0;
#pragma unroll
        for (int b = 0; b < 8; ++b) { bs_l[b] = bs; bs += sc[255][b]; }
        bs_l[8] = bs;
    }
    __syncthreads();
#pragma unroll
    for (int b = 0; b < 8; ++b) offs[t * 8 + b] = bs_l[b] + sc[t][b] - orig[b];
    if (t < 9) bstart[t] = bs_l[t];
    if (t < 8) qtail[t] = 0;
}

// ---------------- binning pass 3: wave-ranked scatter (ballot rank, 8 LDS atomics
// per wave-iter; same-bucket lanes write contiguous slots -> semi-coalesced)
__global__ __launch_bounds__(256) void k_scatter(const int* __restrict__ node_idx,
                                                 const int* __restrict__ edge_idx,
                                                 int E, int chunk, float scale,
                                                 const uint* __restrict__ offs,
                                                 uint2* __restrict__ binned) {
    __shared__ uint lofs[8];
    int tid = threadIdx.x;
    int lane = tid & 63;
    if (tid < 8) lofs[tid] = offs[blockIdx.x * 8 + tid];
    __syncthreads();
    int s = blockIdx.x * chunk;
    int e = s + chunk < E ? s + chunk : E;
    for (int p = s + tid; p < s + ((chunk + 255) & ~255); p += 256) {
        int b = -1;
        uint2 rec = make_uint2(0, 0);
        if (p < e) {
            int ni = __builtin_nontemporal_load(&node_idx[p]);
            int ei = __builtin_nontemporal_load(&edge_idx[p]);
            b = (int)((float)ni * scale);
            b = b < 7 ? b : 7;
            rec = make_uint2((uint)ni | ((uint)ei << 17), (uint)p);
        }
#pragma unroll
        for (int bb = 0; bb < 8; ++bb) {
            ull m = __ballot(b == bb);
            if (m) {
                int leader = (int)(__ffsll((long long)m) - 1);
                uint wb = 0;
                if (lane == leader) wb = atomicAdd(&lofs[bb], (uint)__popcll(m));
                wb = (uint)__shfl((int)wb, leader);
                if (b == bb) {
                    uint rank = (uint)__popcll(m & ((1ull << lane) - 1ull));
                    binned[wb + rank] = rec;
                }
            }
        }
    }
}

// ---------------- per-pair LN+MLP, TRUE XCD-affine: bucket chosen by the
// hardware XCC_ID register + per-bucket atomic work queue — no mapping assumption.
// Node slice (0.8MB) + edge table (1.3MB) L2-resident per XCD. Outputs go to
// val[] CONTIGUOUS (coalesced); un-permute deferred to k_unbin.
__global__ __launch_bounds__(256) void k_pairs_q(const uint2* __restrict__ binned,
                                                 const uint* __restrict__ bstart,
                                                 uint* __restrict__ qtail,
                                                 const signed char* __restrict__ node_pt,
                                                 const signed char* __restrict__ edge_pt,
                                                 const float* __restrict__ GB,
                                                 const float* __restrict__ b2,
                                                 float* __restrict__ val) {
    __shared__ uint sbase;
    uint xcc = get_xcc();
    uint s0 = bstart[xcc], s1 = bstart[xcc + 1];

    int tid = threadIdx.x;
    int l = tid & 3;
    int grp = tid >> 2;  // 0..63

    float G16[16], B16[16], W16[16];
#pragma unroll
    for (int j4 = 0; j4 < 4; ++j4) {
        float4 g = *(const float4*)&GB[128 + l * 16 + j4 * 4];
        float4 b = *(const float4*)&GB[192 + l * 16 + j4 * 4];
        float4 wv = *(const float4*)&GB[256 + l * 16 + j4 * 4];
        G16[j4 * 4 + 0] = g.x; G16[j4 * 4 + 1] = g.y; G16[j4 * 4 + 2] = g.z; G16[j4 * 4 + 3] = g.w;
        B16[j4 * 4 + 0] = b.x; B16[j4 * 4 + 1] = b.y; B16[j4 * 4 + 2] = b.z; B16[j4 * 4 + 3] = b.w;
        W16[j4 * 4 + 0] = wv.x; W16[j4 * 4 + 1] = wv.y; W16[j4 * 4 + 2] = wv.z; W16[j4 * 4 + 3] = wv.w;
    }
    float b2v = b2[0];
    int s_l = (l < 2) ? 1 : 0;
    float two_s = (l < 2) ? 2.0f : 1.0f;

    for (;;) {
        __syncthreads();
        if (tid == 0) sbase = atomicAdd(&qtail[xcc], 512u);
        __syncthreads();
        uint beg = s0 + sbase;
        if (beg >= s1) break;
        uint end = beg + 512u < s1 ? beg + 512u : s1;

        for (uint it = 0; it < 512; it += 256) {
            uint4 qe[4], qn[4];
            uint iv[4];
            bool vld[4];
#pragma unroll
            for (int u = 0; u < 4; ++u) {
                uint i = beg + it + (uint)u * 64 + (uint)grp;
                bool v = i < end;
                uint2 rec = binned[v ? i : beg];
                uint ni = rec.x & 0x1FFFFu;
                uint ei = rec.x >> 17;
                qe[u] = *(const uint4*)&edge_pt[(size_t)ei * 64 + l * 16];
                qn[u] = *(const uint4*)&node_pt[(size_t)ni * 64 + l * 16];
                iv[u] = i;
                vld[u] = v;
            }
#pragma unroll
            for (int u = 0; u < 4; ++u) {
                uint4 e = qe[u], n = qn[u];
                uint uu = lsb8(e.x, e.y) | (lsb8(e.z, e.w) << 8) |
                          (lsb8(n.x, n.y) << 16) | (lsb8(n.z, n.w) << 24);
                uint t0 = __shfl((int)uu, 0, 4);
                uint t1 = __shfl((int)uu, 1, 4);

                float S = 0.5f * ((float)(int)(signed char)(t0 & 0xFFu) +
                                  (float)(int)(signed char)((t0 >> 16) & 0xFFu));
                float Q = 256.0f + 0.75f * ((float)(int)(signed char)((t0 >> 8) & 0xFFu) +
                                            (float)(int)(signed char)(t0 >> 24));
                float esc = bf2f((ushort)(t1 & 0xFFFFu)) * two_s;
                float nsc = bf2f((ushort)(t1 >> 16)) * two_s;

                float mu = S * (1.f / TWO_D);
                float var = fmaf(Q, 1.f / TWO_D, -mu * mu);
                float rstd = rsqrtf(var + LN_EPS);
                float nmu = -mu;

                uint ew[4] = {e.x, e.y, e.z, e.w};
                uint nw[4] = {n.x, n.y, n.z, n.w};
                float acc = 0.f;
#pragma unroll
                for (int j = 0; j < 16; ++j) {
                    int sh = (3 - (j & 3)) * 8;
                    int qa = ((int)(ew[j >> 2] << sh)) >> (24 + s_l);
                    int qb = ((int)(nw[j >> 2] << sh)) >> (24 + s_l);
                    float v = fmaf((float)qa, esc, (float)qb * nsc);
                    float t = fmaf(nmu, G16[j], v);
                    float hv = fmaf(rstd, t, B16[j]);
                    hv = fmaxf(hv, 0.f);
                    acc = fmaf(hv, W16[j], acc);
                }

                acc += __shfl_xor(acc, 1);
                acc += __shfl_xor(acc, 2);

                if (l == 0 && vld[u]) val[iv[u]] = acc + b2v;  // contiguous, coalesced
            }
        }
    }
}

// ---------------- un-permute: coalesced read of (rec, val), scattered nt-store.
// Write-only scatter: no latency dependency, fire-and-forget.
__global__ __launch_bounds__(256) void k_unbin(const uint2* __restrict__ binned,
                                               const float* __restrict__ val,
                                               float* __restrict__ out, int E) {
    int g = blockIdx.x * 256 + threadIdx.x;
    if (g < E) {
        uint p = binned[g].y;
        __builtin_nontemporal_store(val[g], &out[p]);
    }
}

// ---------------- fallback unbinned pairs (R11 path)
__global__ __launch_bounds__(256) void k_pairs(const int* __restrict__ node_idx,
                                               const int* __restrict__ edge_idx,
                                               const signed char* __restrict__ node_pt,
                                               const signed char* __restrict__ edge_pt,
                                               const float* __restrict__ GB,
                                               const float* __restrict__ b2,
                                               float* __restrict__ out, int E) {
    __shared__ int sNi[PPB];
    __shared__ int sEi[PPB];
    int tid = threadIdx.x;
    int base = blockIdx.x * PPB;
    int cnt = E - base;
    cnt = cnt < PPB ? cnt : PPB;
    for (int i = tid; i < cnt; i += 256) {
        sNi[i] = node_idx[base + i];
        sEi[i] = edge_idx[base + i];
    }
    __syncthreads();

    int l = tid & 3;
    int grp = tid >> 2;

    float G16[16], B16[16], W16[16];
#pragma unroll
    for (int j4 = 0; j4 < 4; ++j4) {
        float4 g = *(const float4*)&GB[128 + l * 16 + j4 * 4];
        float4 b = *(const float4*)&GB[192 + l * 16 + j4 * 4];
        float4 wv = *(const float4*)&GB[256 + l * 16 + j4 * 4];
        G16[j4 * 4 + 0] = g.x; G16[j4 * 4 + 1] = g.y; G16[j4 * 4 + 2] = g.z; G16[j4 * 4 + 3] = g.w;
        B16[j4 * 4 + 0] = b.x; B16[j4 * 4 + 1] = b.y; B16[j4 * 4 + 2] = b.z; B16[j4 * 4 + 3] = b.w;
        W16[j4 * 4 + 0] = wv.x; W16[j4 * 4 + 1] = wv.y; W16[j4 * 4 + 2] = wv.z; W16[j4 * 4 + 3] = wv.w;
    }
    float b2v = b2[0];
    int s_l = (l < 2) ? 1 : 0;
    float two_s = (l < 2) ? 2.0f : 1.0f;

    for (int it = 0; it < PPB; it += 256) {
        uint4 qe[4], qn[4];
        int iv[4];
#pragma unroll
        for (int u = 0; u < 4; ++u) {
            int i = it + u * 64 + grp;
            iv[u] = i;
            int ii = i < cnt ? i : 0;
            int ni = sNi[ii];
            int ei = sEi[ii];
            qe[u] = *(const uint4*)&edge_pt[(size_t)ei * 64 + l * 16];
            qn[u] = *(const uint4*)&node_pt[(size_t)ni * 64 + l * 16];
        }
#pragma unroll
        for (int u = 0; u < 4; ++u) {
            uint4 e = qe[u], n = qn[u];
            uint uu = lsb8(e.x, e.y) | (lsb8(e.z, e.w) << 8) |
                      (lsb8(n.x, n.y) << 16) | (lsb8(n.z, n.w) << 24);
            uint t0 = __shfl((int)uu, 0, 4);
            uint t1 = __shfl((int)uu, 1, 4);

            float S = 0.5f * ((float)(int)(signed char)(t0 & 0xFFu) +
                              (float)(int)(signed char)((t0 >> 16) & 0xFFu));
            float Q = 256.0f + 0.75f * ((float)(int)(signed char)((t0 >> 8) & 0xFFu) +
                                        (float)(int)(signed char)(t0 >> 24));
            float esc = bf2f((ushort)(t1 & 0xFFFFu)) * two_s;
            float nsc = bf2f((ushort)(t1 >> 16)) * two_s;

            float mu = S * (1.f / TWO_D);
            float var = fmaf(Q, 1.f / TWO_D, -mu * mu);
            float rstd = rsqrtf(var + LN_EPS);
            float nmu = -mu;

            uint ew[4] = {e.x, e.y, e.z, e.w};
            uint nw[4] = {n.x, n.y, n.z, n.w};
            float acc = 0.f;
#pragma unroll
            for (int j = 0; j < 16; ++j) {
                int sh = (3 - (j & 3)) * 8;
                int qa = ((int)(ew[j >> 2] << sh)) >> (24 + s_l);
                int qb = ((int)(nw[j >> 2] << sh)) >> (24 + s_l);
                float v = fmaf((float)qa, esc, (float)qb * nsc);
                float t = fmaf(nmu, G16[j], v);
                float hv = fmaf(rstd, t, B16[j]);
                hv = fmaxf(hv, 0.f);
                acc = fmaf(hv, W16[j], acc);
            }

            acc += __shfl_xor(acc, 1);
            acc += __shfl_xor(acc, 2);

            if (l == 0 && iv[u] < cnt) out[base + iv[u]] = acc + b2v;
        }
    }
}

extern "C" void kernel_launch(void* const* d_in, const int* in_sizes, int n_in,
                              void* d_out, int out_size, void* d_ws, size_t ws_size,
                              hipStream_t stream) {
    const float* node_feat = (const float*)d_in[0];
    const float* edge_feat = (const float*)d_in[1];
    const float* gamma = (const float*)d_in[2];
    const float* beta = (const float*)d_in[3];
    const float* W1 = (const float*)d_in[4];
    const float* b1 = (const float*)d_in[5];
    const float* W2 = (const float*)d_in[6];
    const float* b2 = (const float*)d_in[7];
    const int* node_idx = (const int*)d_in[8];
    const int* edge_idx = (const int*)d_in[9];

    int n_nodes = in_sizes[0] / DD;
    int n_edges = in_sizes[1] / DD;
    int E = in_sizes[8];

    char* wsb = (char*)d_ws;
    size_t o = 0;
    float* GB = (float*)(wsb + o); o += 2048;          // 512 floats
    uint* hist = (uint*)(wsb + o); o += 256 * 8 * 4;   // 8KB
    uint* offs = (uint*)(wsb + o); o += 256 * 8 * 4;   // 8KB
    uint* bstart = (uint*)(wsb + o); o += 64;
    uint* qtail = (uint*)(wsb + o); o += 64;
    o = (o + 127) & ~(size_t)127;
    signed char* node_pt = (signed char*)(wsb + o); o += (size_t)n_nodes * 64;
    signed char* edge_pt = (signed char*)(wsb + o); o += (size_t)n_edges * 64;
    o = (o + 127) & ~(size_t)127;
    uint2* binned = (uint2*)(wsb + o); o += (size_t)E * sizeof(uint2);
    float* val = (float*)(wsb + o);
    size_t need = o + (size_t)E * sizeof(float);
    // ~20 MB total

    bool can_bin = (n_nodes <= (1 << 17)) && (n_edges <= (1 << 15)) && (ws_size >= need);

    int nbN = (n_nodes + 127) / 128;
    int nbE = (n_edges + 127) / 128;
    int chunk = (E + 255) / 256;
    float scale = 8.0f / (float)n_nodes;

    if (can_bin) {
        k_hist<<<256, 256, 0, stream>>>(node_idx, E, chunk, scale, hist);
        k_scan<<<1, 256, 0, stream>>>(hist, offs, bstart, qtail);
        k_scatter<<<256, 256, 0, stream>>>(node_idx, edge_idx, E, chunk, scale, offs, binned);
    }

    k_fused<<<1 + nbN + nbE, 256, 0, stream>>>(node_feat, n_nodes, nbN,
                                               edge_feat, n_edges,
                                               gamma, beta, W1, b1, W2,
                                               node_pt, edge_pt, GB);

    if (can_bin) {
        k_pairs_q<<<2048, 256, 0, stream>>>(binned, bstart, qtail, node_pt, edge_pt,
                                            GB, b2, val);
        k_unbin<<<(E + 255) / 256, 256, 0, stream>>>(binned, val, (float*)d_out, E);
    } else {
        k_pairs<<<(E + PPB - 1) / PPB, 256, 0, stream>>>(node_idx, edge_idx, node_pt, edge_pt,
                                                         GB, b2, (float*)d_out, E);
    }
}

// Round 15
// 53.393 us; speedup vs baseline: 2.6282x; 2.6282x over previous
//
#include <hip/hip_runtime.h>

#define LN_EPS 1e-5f
#define DD 128
#define TWO_D 256
#define HH 64
#define PPB 512   // pairs per block in k_pairs

typedef unsigned int uint;
typedef unsigned short ushort;
typedef __attribute__((ext_vector_type(8))) short short8v;   // 8 bf16 (4 VGPRs)
typedef __attribute__((ext_vector_type(4))) float f32x4;     // MFMA accumulator

__device__ __forceinline__ ushort f2bf(float f) {
    uint u = __float_as_uint(f);
    u += 0x7FFFu + ((u >> 16) & 1u);  // round-to-nearest-even
    return (ushort)(u >> 16);
}
__device__ __forceinline__ float bf2f(ushort h) {
    return __uint_as_float(((uint)h) << 16);
}
__device__ __forceinline__ int clampi(int v, int lo, int hi) {
    return v < lo ? lo : (v > hi ? hi : v);
}
// Gather the 8 LSBs of the 8 bytes in (a,b); byte pos k' -> bit (7-k') of result
__device__ __forceinline__ uint lsb8(uint a, uint b) {
    uint nx = (((a & 0x01010101u) * 0x08040201u) >> 24) & 0xFu;
    uint ny = (((b & 0x01010101u) * 0x08040201u) >> 24) & 0xFu;
    return (nx << 4) | ny;
}

// ---------------- fused proj: block 0 = prep; 128 rows/block via MFMA;
// 64B int8 rows, h-permuted (byte k holds h=(k&3)*16+(k>>2)); bytes 0..31 are 7-bit,
// LSBs carry payload S_q8 | Q_q8<<8 | bf16(scale)<<16.
// GB floats: [0..63] G, [64..127] B1c, [128..191] Gp, [192..255] Bp, [256..319] Wp
__global__ __launch_bounds__(256) void k_fused(
    const float* __restrict__ node_feat, int n_nodes, int nbN,
    const float* __restrict__ edge_feat, int n_edges,
    const float* __restrict__ gamma, const float* __restrict__ beta,
    const float* __restrict__ W1, const float* __restrict__ b1,
    const float* __restrict__ W2,
    signed char* __restrict__ node_pt, signed char* __restrict__ edge_pt,
    float* __restrict__ GB) {
    int bid = blockIdx.x;
    int tid = threadIdx.x;

    if (bid == 0) {
        if (tid < 128) {
            int h = tid & 63;
            bool isB = tid >= 64;
            float acc = isB ? b1[h] : 0.f;
            const float* coef = isB ? beta : gamma;
#pragma unroll 8
            for (int d = 0; d < TWO_D; ++d)
                acc = fmaf(coef[d], W1[d * HH + h], acc);
            GB[tid] = acc;
        }
        __syncthreads();
        if (tid < 64) {
            int h = ((tid & 3) * 16) + (tid >> 2);   // byte pos tid holds h
            GB[128 + tid] = GB[h];
            GB[192 + tid] = GB[64 + h];
            GB[256 + tid] = W2[h];
        }
        return;
    }

    const float* feat;
    int nrows, gofs, rbase0;
    signed char* pt;
    if (bid <= nbN) {
        feat = node_feat; nrows = n_nodes; gofs = 128;
        rbase0 = (bid - 1) * 128; pt = node_pt;
    } else {
        feat = edge_feat; nrows = n_edges; gofs = 0;
        rbase0 = (bid - 1 - nbN) * 128; pt = edge_pt;
    }

    __shared__ __align__(16) char lds[49664];
    uint* sqLDS = (uint*)(lds + 49152);

    {
        int l = tid & 63;
        int w = tid >> 6;
#pragma unroll
        for (int ci = 0; ci < 4; ++ci) {
            int combo = ci * 4 + w;
            int ks = combo & 3;
            int ht = combo >> 2;
            int kbase = gofs + ks * 32 + (l >> 4) * 8;
            int h = ht * 16 + (l & 15);
            short8v v;
#pragma unroll
            for (int j = 0; j < 8; ++j)
                v[j] = (short)f2bf(gamma[kbase + j] * W1[(size_t)(kbase + j) * HH + h]);
            *(short8v*)(lds + 32768 + combo * 1024 + l * 16) = v;
        }
    }

    {
        float4 tmp[16];
#pragma unroll
        for (int u = 0; u < 16; ++u) {
            int F4 = u * 256 + tid;
            int r = F4 >> 5;
            int rg = rbase0 + r;
            rg = rg < nrows ? rg : (nrows - 1);
            int c4 = (F4 & 31) * 4;
            tmp[u] = *(const float4*)&feat[(size_t)rg * DD + c4];
        }
#pragma unroll
        for (int u = 0; u < 16; ++u) {
            int F4 = u * 256 + tid;
            int r = F4 >> 5;
            int c4 = (F4 & 31) * 4;
            uint2 wv;
            wv.x = (uint)f2bf(tmp[u].x) | ((uint)f2bf(tmp[u].y) << 16);
            wv.y = (uint)f2bf(tmp[u].z) | ((uint)f2bf(tmp[u].w) << 16);
            int byte = (r * 256 + c4 * 2) ^ ((r & 7) << 4);
            *(uint2*)(lds + byte) = wv;
        }
    }

    __syncthreads();

    int w = tid >> 6;
    int lane = tid & 63;
    f32x4 acc[2][4];
#pragma unroll
    for (int i = 0; i < 2; ++i)
#pragma unroll
        for (int j = 0; j < 4; ++j) acc[i][j] = (f32x4){0.f, 0.f, 0.f, 0.f};

    int arow_lo = lane & 15;
    int akofs = (lane >> 4) * 8;
#pragma unroll
    for (int ks = 0; ks < 4; ++ks) {
        int kk = ks * 32 + akofs;
        int rr0 = (2 * w) * 16 + arow_lo;
        int rr1 = rr0 + 16;
        short8v a0 = *(const short8v*)(lds + ((rr0 * 256 + kk * 2) ^ ((rr0 & 7) << 4)));
        short8v a1 = *(const short8v*)(lds + ((rr1 * 256 + kk * 2) ^ ((rr1 & 7) << 4)));
#pragma unroll
        for (int ht = 0; ht < 4; ++ht) {
            short8v b = *(const short8v*)(lds + 32768 + (ht * 4 + ks) * 1024 + lane * 16);
            acc[0][ht] = __builtin_amdgcn_mfma_f32_16x16x32_bf16(a0, b, acc[0][ht], 0, 0, 0);
            acc[1][ht] = __builtin_amdgcn_mfma_f32_16x16x32_bf16(a1, b, acc[1][ht], 0, 0, 0);
        }
    }

    {
        int row = tid >> 1, half = tid & 1;
        float s = 0.f, q = 0.f;
#pragma unroll
        for (int i = 0; i < 8; ++i) {
            int byte = (row * 256 + half * 128 + i * 16) ^ ((row & 7) << 4);
            short8v v = *(const short8v*)(lds + byte);
#pragma unroll
            for (int j = 0; j < 8; ++j) {
                float x = bf2f((ushort)v[j]);
                s += x;
                q = fmaf(x, x, q);
            }
        }
        s += __shfl_xor(s, 1);
        q += __shfl_xor(q, 1);
        if (half == 0) {
            int sq = clampi(__float2int_rn(2.0f * s), -127, 127);
            int qq = clampi(__float2int_rn((q - 128.0f) * (1.0f / 0.75f)), -127, 127);
            sqLDS[row] = ((uint)sq & 0xFFu) | (((uint)qq & 0xFFu) << 8);
        }
    }

    __syncthreads();

    {
        int colh = lane & 15;
        int rquad = lane >> 4;
#pragma unroll
        for (int rt = 0; rt < 2; ++rt)
#pragma unroll
            for (int reg = 0; reg < 4; ++reg) {
                float m = fmaxf(fmaxf(fabsf(acc[rt][0][reg]), fabsf(acc[rt][1][reg])),
                                fmaxf(fabsf(acc[rt][2][reg]), fabsf(acc[rt][3][reg])));
                m = fmaxf(m, __shfl_xor(m, 1));
                m = fmaxf(m, __shfl_xor(m, 2));
                m = fmaxf(m, __shfl_xor(m, 4));
                m = fmaxf(m, __shfl_xor(m, 8));
                m = fmaxf(m, 1e-20f);
                float inv = 127.0f / m;
                int rl = (2 * w + rt) * 16 + rquad * 4 + reg;
                uint P = sqLDS[rl] | ((uint)f2bf(m * (1.0f / 127.0f)) << 16);
                uint pk = 0;
#pragma unroll
                for (int ht = 0; ht < 4; ++ht) {
                    uint byte;
                    if (colh < 8) {
                        int kpos = colh * 4 + ht;
                        uint V = (P >> (8 * (kpos >> 3))) & 0xFFu;
                        uint bit = (V >> (7 - (kpos & 7))) & 1u;
                        int q7 = clampi(__float2int_rn(acc[rt][ht][reg] * inv * 0.5f), -63, 63);
                        byte = (((uint)q7 << 1) | bit) & 0xFFu;
                    } else {
                        byte = (uint)__float2int_rn(acc[rt][ht][reg] * inv) & 0xFFu;
                    }
                    pk |= byte << (8 * ht);
                }
                if (rbase0 + rl < nrows)
                    *(uint*)&pt[(size_t)(rbase0 + rl) * 64 + colh * 4] = pk;
            }
    }
}

// ---- per-pair math on one gathered (edge,node) row pair (4 lanes/pair)
__device__ __forceinline__ float pair_compute(uint4 e, uint4 n,
                                              const float G16[16], const float B16[16],
                                              const float W16[16], int s_l, float two_s) {
    uint uu = lsb8(e.x, e.y) | (lsb8(e.z, e.w) << 8) |
              (lsb8(n.x, n.y) << 16) | (lsb8(n.z, n.w) << 24);
    uint t0 = __shfl((int)uu, 0, 4);   // lane0: eS | eQ<<8 | nS<<16 | nQ<<24
    uint t1 = __shfl((int)uu, 1, 4);   // lane1: e_scale bf16 | n_scale bf16 <<16

    float S = 0.5f * ((float)(int)(signed char)(t0 & 0xFFu) +
                      (float)(int)(signed char)((t0 >> 16) & 0xFFu));
    float Q = 256.0f + 0.75f * ((float)(int)(signed char)((t0 >> 8) & 0xFFu) +
                                (float)(int)(signed char)(t0 >> 24));
    float esc = bf2f((ushort)(t1 & 0xFFFFu)) * two_s;
    float nsc = bf2f((ushort)(t1 >> 16)) * two_s;

    float mu = S * (1.f / TWO_D);
    float var = fmaf(Q, 1.f / TWO_D, -mu * mu);
    float rstd = rsqrtf(var + LN_EPS);
    float nmu = -mu;

    uint ew[4] = {e.x, e.y, e.z, e.w};
    uint nw[4] = {n.x, n.y, n.z, n.w};
    float acc = 0.f;
#pragma unroll
    for (int j = 0; j < 16; ++j) {
        int sh = (3 - (j & 3)) * 8;
        int qa = ((int)(ew[j >> 2] << sh)) >> (24 + s_l);
        int qb = ((int)(nw[j >> 2] << sh)) >> (24 + s_l);
        float v = fmaf((float)qa, esc, (float)qb * nsc);
        float t = fmaf(nmu, G16[j], v);
        float hv = fmaf(rstd, t, B16[j]);
        hv = fmaxf(hv, 0.f);
        acc = fmaf(hv, W16[j], acc);
    }

    acc += __shfl_xor(acc, 1);
    acc += __shfl_xor(acc, 2);
    return acc;
}

// ---------------- per-pair fused LN+MLP via int8 tables w/ embedded stats.
// 4 lanes/pair, uint4 row loads. Fully-unrolled 2-deep software pipeline:
// ALL 16 gathers of both 256-pair batches issued before any compute, so
// batch-B latency hides under batch-A compute (tests per-wave latency exposure).
__global__ __launch_bounds__(256) void k_pairs(const int* __restrict__ node_idx,
                                               const int* __restrict__ edge_idx,
                                               const signed char* __restrict__ node_pt,
                                               const signed char* __restrict__ edge_pt,
                                               const float* __restrict__ GB,
                                               const float* __restrict__ b2,
                                               float* __restrict__ out, int E) {
    __shared__ int sNi[PPB];
    __shared__ int sEi[PPB];
    int tid = threadIdx.x;
    int base = blockIdx.x * PPB;
    int cnt = E - base;
    cnt = cnt < PPB ? cnt : PPB;
    for (int i = tid; i < cnt; i += 256) {
        sNi[i] = node_idx[base + i];
        sEi[i] = edge_idx[base + i];
    }
    __syncthreads();

    int l = tid & 3;
    int grp = tid >> 2;  // 0..63

    float G16[16], B16[16], W16[16];
#pragma unroll
    for (int j4 = 0; j4 < 4; ++j4) {
        float4 g = *(const float4*)&GB[128 + l * 16 + j4 * 4];
        float4 b = *(const float4*)&GB[192 + l * 16 + j4 * 4];
        float4 wv = *(const float4*)&GB[256 + l * 16 + j4 * 4];
        G16[j4 * 4 + 0] = g.x; G16[j4 * 4 + 1] = g.y; G16[j4 * 4 + 2] = g.z; G16[j4 * 4 + 3] = g.w;
        B16[j4 * 4 + 0] = b.x; B16[j4 * 4 + 1] = b.y; B16[j4 * 4 + 2] = b.z; B16[j4 * 4 + 3] = b.w;
        W16[j4 * 4 + 0] = wv.x; W16[j4 * 4 + 1] = wv.y; W16[j4 * 4 + 2] = wv.z; W16[j4 * 4 + 3] = wv.w;
    }
    float b2v = b2[0];
    int s_l = (l < 2) ? 1 : 0;          // lanes 0,1 hold 7-bit bytes (LSB stolen)
    float two_s = (l < 2) ? 2.0f : 1.0f;

    // ---- issue ALL gathers for both batches (16 uint4 loads in flight per lane)
    uint4 qeA[4], qnA[4], qeB[4], qnB[4];
#pragma unroll
    for (int u = 0; u < 4; ++u) {
        int i = u * 64 + grp;
        int ii = i < cnt ? i : 0;
        int ni = sNi[ii];
        int ei = sEi[ii];
        qeA[u] = *(const uint4*)&edge_pt[(size_t)ei * 64 + l * 16];
        qnA[u] = *(const uint4*)&node_pt[(size_t)ni * 64 + l * 16];
    }
#pragma unroll
    for (int u = 0; u < 4; ++u) {
        int i = 256 + u * 64 + grp;
        int ii = i < cnt ? i : 0;
        int ni = sNi[ii];
        int ei = sEi[ii];
        qeB[u] = *(const uint4*)&edge_pt[(size_t)ei * 64 + l * 16];
        qnB[u] = *(const uint4*)&node_pt[(size_t)ni * 64 + l * 16];
    }

    // ---- compute batch A (batch B loads still in flight)
#pragma unroll
    for (int u = 0; u < 4; ++u) {
        float a = pair_compute(qeA[u], qnA[u], G16, B16, W16, s_l, two_s);
        int i = u * 64 + grp;
        if (l == 0 && i < cnt) out[base + i] = a + b2v;
    }
    // ---- compute batch B
#pragma unroll
    for (int u = 0; u < 4; ++u) {
        float a = pair_compute(qeB[u], qnB[u], G16, B16, W16, s_l, two_s);
        int i = 256 + u * 64 + grp;
        if (l == 0 && i < cnt) out[base + i] = a + b2v;
    }
}

extern "C" void kernel_launch(void* const* d_in, const int* in_sizes, int n_in,
                              void* d_out, int out_size, void* d_ws, size_t ws_size,
                              hipStream_t stream) {
    const float* node_feat = (const float*)d_in[0];
    const float* edge_feat = (const float*)d_in[1];
    const float* gamma = (const float*)d_in[2];
    const float* beta = (const float*)d_in[3];
    const float* W1 = (const float*)d_in[4];
    const float* b1 = (const float*)d_in[5];
    const float* W2 = (const float*)d_in[6];
    const float* b2 = (const float*)d_in[7];
    const int* node_idx = (const int*)d_in[8];
    const int* edge_idx = (const int*)d_in[9];

    int n_nodes = in_sizes[0] / DD;
    int n_edges = in_sizes[1] / DD;
    int E = in_sizes[8];

    char* wsb = (char*)d_ws;
    size_t o = 0;
    float* GB = (float*)(wsb + o); o += 2048;   // 512 floats
    o = (o + 127) & ~(size_t)127;
    signed char* node_pt = (signed char*)(wsb + o); o += (size_t)n_nodes * 64;
    signed char* edge_pt = (signed char*)(wsb + o); o += (size_t)n_edges * 64;
    // total ws ~= 7.7 MB

    int nbN = (n_nodes + 127) / 128;
    int nbE = (n_edges + 127) / 128;

    k_fused<<<1 + nbN + nbE, 256, 0, stream>>>(node_feat, n_nodes, nbN,
                                               edge_feat, n_edges,
                                               gamma, beta, W1, b1, W2,
                                               node_pt, edge_pt, GB);
    k_pairs<<<(E + PPB - 1) / PPB, 256, 0, stream>>>(node_idx, edge_idx, node_pt, edge_pt,
                                                     GB, b2, (float*)d_out, E);
}

// Round 17
// 51.013 us; speedup vs baseline: 2.7508x; 1.0467x over previous
//
#include <hip/hip_runtime.h>

#define LN_EPS 1e-5f
#define DD 128
#define TWO_D 256
#define HH 64
#define PPB 512   // pairs per block in k_pairs

typedef unsigned int uint;
typedef unsigned short ushort;
typedef __attribute__((ext_vector_type(8))) short short8v;   // 8 bf16 (4 VGPRs)
typedef __attribute__((ext_vector_type(4))) float f32x4;     // MFMA accumulator

__device__ __forceinline__ ushort f2bf(float f) {
    uint u = __float_as_uint(f);
    u += 0x7FFFu + ((u >> 16) & 1u);  // round-to-nearest-even
    return (ushort)(u >> 16);
}
__device__ __forceinline__ float bf2f(ushort h) {
    return __uint_as_float(((uint)h) << 16);
}
__device__ __forceinline__ int clampi(int v, int lo, int hi) {
    return v < lo ? lo : (v > hi ? hi : v);
}
// Gather the 8 LSBs of the 8 bytes in (a,b); byte pos k' -> bit (7-k') of result
__device__ __forceinline__ uint lsb8(uint a, uint b) {
    uint nx = (((a & 0x01010101u) * 0x08040201u) >> 24) & 0xFu;
    uint ny = (((b & 0x01010101u) * 0x08040201u) >> 24) & 0xFu;
    return (nx << 4) | ny;
}

// ---------------- fused proj: block 0 = prep (G, B1c + permuted Gp/Bp/Wp);
// blocks [1,nbN] = node proj; blocks (nbN, nbN+nbE] = edge proj. 128 rows/block MFMA.
// Row = 64 B int8 (per-row scale), h-permuted: byte k holds h=(k&3)*16+(k>>2).
// Bytes 0..31 are 7-bit values; their LSBs carry payload P =
//   S_q8 | Q_q8<<8 | bf16(scale)<<16, bit for byte pos k = (P_byte[k>>3] >> (7-(k&7)))&1.
// S_q8 = round(2*S_side), Q_q8 = round((Q_side-128)/0.75).
// GB layout (floats): [0..63] G, [64..127] B1c, [128..191] Gp, [192..255] Bp, [256..319] Wp
__global__ __launch_bounds__(256) void k_fused(
    const float* __restrict__ node_feat, int n_nodes, int nbN,
    const float* __restrict__ edge_feat, int n_edges,
    const float* __restrict__ gamma, const float* __restrict__ beta,
    const float* __restrict__ W1, const float* __restrict__ b1,
    const float* __restrict__ W2,
    signed char* __restrict__ node_pt, signed char* __restrict__ edge_pt,
    float* __restrict__ GB) {
    int bid = blockIdx.x;
    int tid = threadIdx.x;

    if (bid == 0) {
        if (tid < 128) {
            int h = tid & 63;
            bool isB = tid >= 64;
            float acc = isB ? b1[h] : 0.f;
            const float* coef = isB ? beta : gamma;
#pragma unroll 8
            for (int d = 0; d < TWO_D; ++d)
                acc = fmaf(coef[d], W1[d * HH + h], acc);
            GB[tid] = acc;
        }
        __syncthreads();
        if (tid < 64) {
            int h = ((tid & 3) * 16) + (tid >> 2);   // byte pos tid holds h
            GB[128 + tid] = GB[h];
            GB[192 + tid] = GB[64 + h];
            GB[256 + tid] = W2[h];
        }
        return;
    }

    const float* feat;
    int nrows, gofs, rbase0;
    signed char* pt;
    if (bid <= nbN) {
        feat = node_feat; nrows = n_nodes; gofs = 128;
        rbase0 = (bid - 1) * 128; pt = node_pt;
    } else {
        feat = edge_feat; nrows = n_edges; gofs = 0;
        rbase0 = (bid - 1 - nbN) * 128; pt = edge_pt;
    }

    // LDS: [0,32K) featA bf16 [128][128], byte=(r*256+k*2)^((r&7)<<4)
    //      [32K,48K) gwB packed MFMA-B frags
    //      [48K,48K+512) per-row packed (S_q8 | Q_q8<<8)
    __shared__ __align__(16) char lds[49664];
    uint* sqLDS = (uint*)(lds + 49152);

    // ---- stage gwB in MFMA B-fragment order: B[k][h] = gamma[gofs+k]*W1[gofs+k][h]
    {
        int l = tid & 63;
        int w = tid >> 6;  // 0..3
#pragma unroll
        for (int ci = 0; ci < 4; ++ci) {
            int combo = ci * 4 + w;           // = ht*4 + ks
            int ks = combo & 3;
            int ht = combo >> 2;
            int kbase = gofs + ks * 32 + (l >> 4) * 8;
            int h = ht * 16 + (l & 15);
            short8v v;
#pragma unroll
            for (int j = 0; j < 8; ++j)
                v[j] = (short)f2bf(gamma[kbase + j] * W1[(size_t)(kbase + j) * HH + h]);
            *(short8v*)(lds + 32768 + combo * 1024 + l * 16) = v;
        }
    }

    // ---- stage featA: 64KB contiguous f32 -> bf16 LDS tile
    {
        float4 tmp[16];
#pragma unroll
        for (int u = 0; u < 16; ++u) {
            int F4 = u * 256 + tid;
            int r = F4 >> 5;
            int rg = rbase0 + r;
            rg = rg < nrows ? rg : (nrows - 1);
            int c4 = (F4 & 31) * 4;
            tmp[u] = *(const float4*)&feat[(size_t)rg * DD + c4];
        }
#pragma unroll
        for (int u = 0; u < 16; ++u) {
            int F4 = u * 256 + tid;
            int r = F4 >> 5;
            int c4 = (F4 & 31) * 4;
            uint2 wv;
            wv.x = (uint)f2bf(tmp[u].x) | ((uint)f2bf(tmp[u].y) << 16);
            wv.y = (uint)f2bf(tmp[u].z) | ((uint)f2bf(tmp[u].w) << 16);
            int byte = (r * 256 + c4 * 2) ^ ((r & 7) << 4);
            *(uint2*)(lds + byte) = wv;
        }
    }

    __syncthreads();

    // ---- MFMA: wave w computes rows [32w, 32w+32) x 64 h
    int w = tid >> 6;
    int lane = tid & 63;
    f32x4 acc[2][4];
#pragma unroll
    for (int i = 0; i < 2; ++i)
#pragma unroll
        for (int j = 0; j < 4; ++j) acc[i][j] = (f32x4){0.f, 0.f, 0.f, 0.f};

    int arow_lo = lane & 15;
    int akofs = (lane >> 4) * 8;
#pragma unroll
    for (int ks = 0; ks < 4; ++ks) {
        int kk = ks * 32 + akofs;
        int rr0 = (2 * w) * 16 + arow_lo;
        int rr1 = rr0 + 16;
        short8v a0 = *(const short8v*)(lds + ((rr0 * 256 + kk * 2) ^ ((rr0 & 7) << 4)));
        short8v a1 = *(const short8v*)(lds + ((rr1 * 256 + kk * 2) ^ ((rr1 & 7) << 4)));
#pragma unroll
        for (int ht = 0; ht < 4; ++ht) {
            short8v b = *(const short8v*)(lds + 32768 + (ht * 4 + ks) * 1024 + lane * 16);
            acc[0][ht] = __builtin_amdgcn_mfma_f32_16x16x32_bf16(a0, b, acc[0][ht], 0, 0, 0);
            acc[1][ht] = __builtin_amdgcn_mfma_f32_16x16x32_bf16(a1, b, acc[1][ht], 0, 0, 0);
        }
    }

    // ---- sums from LDS bf16 tile (2 threads per row) -> quantized into sqLDS
    {
        int row = tid >> 1, half = tid & 1;
        float s = 0.f, q = 0.f;
#pragma unroll
        for (int i = 0; i < 8; ++i) {
            int byte = (row * 256 + half * 128 + i * 16) ^ ((row & 7) << 4);
            short8v v = *(const short8v*)(lds + byte);
#pragma unroll
            for (int j = 0; j < 8; ++j) {
                float x = bf2f((ushort)v[j]);
                s += x;
                q = fmaf(x, x, q);
            }
        }
        s += __shfl_xor(s, 1);
        q += __shfl_xor(q, 1);
        if (half == 0) {
            int sq = clampi(__float2int_rn(2.0f * s), -127, 127);
            int qq = clampi(__float2int_rn((q - 128.0f) * (1.0f / 0.75f)), -127, 127);
            sqLDS[row] = ((uint)sq & 0xFFu) | (((uint)qq & 0xFFu) << 8);
        }
    }

    __syncthreads();  // sqLDS visible to epilogue

    // ---- epilogue: int8/int7 quantize from regs; D frag: col=lane&15, row=(lane>>4)*4+reg
    {
        int colh = lane & 15;
        int rquad = lane >> 4;
#pragma unroll
        for (int rt = 0; rt < 2; ++rt)
#pragma unroll
            for (int reg = 0; reg < 4; ++reg) {
                float m = fmaxf(fmaxf(fabsf(acc[rt][0][reg]), fabsf(acc[rt][1][reg])),
                                fmaxf(fabsf(acc[rt][2][reg]), fabsf(acc[rt][3][reg])));
                m = fmaxf(m, __shfl_xor(m, 1));
                m = fmaxf(m, __shfl_xor(m, 2));
                m = fmaxf(m, __shfl_xor(m, 4));
                m = fmaxf(m, __shfl_xor(m, 8));
                m = fmaxf(m, 1e-20f);
                float inv = 127.0f / m;
                int rl = (2 * w + rt) * 16 + rquad * 4 + reg;
                uint P = sqLDS[rl] | ((uint)f2bf(m * (1.0f / 127.0f)) << 16);
                uint pk = 0;
#pragma unroll
                for (int ht = 0; ht < 4; ++ht) {
                    uint byte;
                    if (colh < 8) {
                        int kpos = colh * 4 + ht;               // byte pos 0..31
                        uint V = (P >> (8 * (kpos >> 3))) & 0xFFu;
                        uint bit = (V >> (7 - (kpos & 7))) & 1u;
                        int q7 = clampi(__float2int_rn(acc[rt][ht][reg] * inv * 0.5f), -63, 63);
                        byte = (((uint)q7 << 1) | bit) & 0xFFu;
                    } else {
                        byte = (uint)__float2int_rn(acc[rt][ht][reg] * inv) & 0xFFu;
                    }
                    pk |= byte << (8 * ht);
                }
                if (rbase0 + rl < nrows)
                    *(uint*)&pt[(size_t)(rbase0 + rl) * 64 + colh * 4] = pk;
            }
    }
}

// ---------------- per-pair fused LN+MLP via int8 tables w/ embedded stats.
// 4 lanes/pair; lane l holds bytes 16l..16l+15 (one uint4). Explicit 4-deep
// prefetch: 8 independent 16B gathers in flight per group before any use.
__global__ __launch_bounds__(256) void k_pairs(const int* __restrict__ node_idx,
                                               const int* __restrict__ edge_idx,
                                               const signed char* __restrict__ node_pt,
                                               const signed char* __restrict__ edge_pt,
                                               const float* __restrict__ GB,
                                               const float* __restrict__ b2,
                                               float* __restrict__ out, int E) {
    __shared__ int sNi[PPB];
    __shared__ int sEi[PPB];
    int tid = threadIdx.x;
    int base = blockIdx.x * PPB;
    int cnt = E - base;
    cnt = cnt < PPB ? cnt : PPB;
    for (int i = tid; i < cnt; i += 256) {
        sNi[i] = node_idx[base + i];
        sEi[i] = edge_idx[base + i];
    }
    __syncthreads();

    int l = tid & 3;
    int grp = tid >> 2;  // 0..63

    float G16[16], B16[16], W16[16];
#pragma unroll
    for (int j4 = 0; j4 < 4; ++j4) {
        float4 g = *(const float4*)&GB[128 + l * 16 + j4 * 4];
        float4 b = *(const float4*)&GB[192 + l * 16 + j4 * 4];
        float4 wv = *(const float4*)&GB[256 + l * 16 + j4 * 4];
        G16[j4 * 4 + 0] = g.x; G16[j4 * 4 + 1] = g.y; G16[j4 * 4 + 2] = g.z; G16[j4 * 4 + 3] = g.w;
        B16[j4 * 4 + 0] = b.x; B16[j4 * 4 + 1] = b.y; B16[j4 * 4 + 2] = b.z; B16[j4 * 4 + 3] = b.w;
        W16[j4 * 4 + 0] = wv.x; W16[j4 * 4 + 1] = wv.y; W16[j4 * 4 + 2] = wv.z; W16[j4 * 4 + 3] = wv.w;
    }
    float b2v = b2[0];
    int s_l = (l < 2) ? 1 : 0;          // lanes 0,1 hold 7-bit bytes (LSB stolen)
    float two_s = (l < 2) ? 2.0f : 1.0f;

    for (int it = 0; it < PPB; it += 256) {
        uint4 qe[4], qn[4];
        int iv[4];
#pragma unroll
        for (int u = 0; u < 4; ++u) {
            int i = it + u * 64 + grp;
            iv[u] = i;
            int ii = i < cnt ? i : 0;
            int ni = sNi[ii];
            int ei = sEi[ii];
            qe[u] = *(const uint4*)&edge_pt[(size_t)ei * 64 + l * 16];
            qn[u] = *(const uint4*)&node_pt[(size_t)ni * 64 + l * 16];
        }
#pragma unroll
        for (int u = 0; u < 4; ++u) {
            uint4 e = qe[u], n = qn[u];
            uint uu = lsb8(e.x, e.y) | (lsb8(e.z, e.w) << 8) |
                      (lsb8(n.x, n.y) << 16) | (lsb8(n.z, n.w) << 24);
            uint t0 = __shfl((int)uu, 0, 4);   // lane0: eS | eQ<<8 | nS<<16 | nQ<<24
            uint t1 = __shfl((int)uu, 1, 4);   // lane1: e_scale bf16 | n_scale bf16 <<16

            float S = 0.5f * ((float)(int)(signed char)(t0 & 0xFFu) +
                              (float)(int)(signed char)((t0 >> 16) & 0xFFu));
            float Q = 256.0f + 0.75f * ((float)(int)(signed char)((t0 >> 8) & 0xFFu) +
                                        (float)(int)(signed char)(t0 >> 24));
            float esc = bf2f((ushort)(t1 & 0xFFFFu)) * two_s;
            float nsc = bf2f((ushort)(t1 >> 16)) * two_s;

            float mu = S * (1.f / TWO_D);
            float var = fmaf(Q, 1.f / TWO_D, -mu * mu);
            float rstd = rsqrtf(var + LN_EPS);
            float nmu = -mu;

            uint ew[4] = {e.x, e.y, e.z, e.w};
            uint nw[4] = {n.x, n.y, n.z, n.w};
            float acc = 0.f;
#pragma unroll
            for (int j = 0; j < 16; ++j) {
                int sh = (3 - (j & 3)) * 8;
                int qa = ((int)(ew[j >> 2] << sh)) >> (24 + s_l);
                int qb = ((int)(nw[j >> 2] << sh)) >> (24 + s_l);
                float v = fmaf((float)qa, esc, (float)qb * nsc);
                float t = fmaf(nmu, G16[j], v);
                float hv = fmaf(rstd, t, B16[j]);
                hv = fmaxf(hv, 0.f);
                acc = fmaf(hv, W16[j], acc);
            }

            acc += __shfl_xor(acc, 1);
            acc += __shfl_xor(acc, 2);

            if (l == 0 && iv[u] < cnt) out[base + iv[u]] = acc + b2v;
        }
    }
}

extern "C" void kernel_launch(void* const* d_in, const int* in_sizes, int n_in,
                              void* d_out, int out_size, void* d_ws, size_t ws_size,
                              hipStream_t stream) {
    const float* node_feat = (const float*)d_in[0];
    const float* edge_feat = (const float*)d_in[1];
    const float* gamma = (const float*)d_in[2];
    const float* beta = (const float*)d_in[3];
    const float* W1 = (const float*)d_in[4];
    const float* b1 = (const float*)d_in[5];
    const float* W2 = (const float*)d_in[6];
    const float* b2 = (const float*)d_in[7];
    const int* node_idx = (const int*)d_in[8];
    const int* edge_idx = (const int*)d_in[9];

    int n_nodes = in_sizes[0] / DD;
    int n_edges = in_sizes[1] / DD;
    int E = in_sizes[8];

    char* wsb = (char*)d_ws;
    size_t o = 0;
    float* GB = (float*)(wsb + o); o += 2048;   // 512 floats
    o = (o + 127) & ~(size_t)127;
    signed char* node_pt = (signed char*)(wsb + o); o += (size_t)n_nodes * 64;
    signed char* edge_pt = (signed char*)(wsb + o); o += (size_t)n_edges * 64;
    // total ws ~= 7.7 MB

    int nbN = (n_nodes + 127) / 128;
    int nbE = (n_edges + 127) / 128;

    k_fused<<<1 + nbN + nbE, 256, 0, stream>>>(node_feat, n_nodes, nbN,
                                               edge_feat, n_edges,
                                               gamma, beta, W1, b1, W2,
                                               node_pt, edge_pt, GB);
    k_pairs<<<(E + PPB - 1) / PPB, 256, 0, stream>>>(node_idx, edge_idx, node_pt, edge_pt,
                                                     GB, b2, (float*)d_out, E);
}